// Round 9
// baseline (3217.756 us; speedup 1.0000x reference)
//
#include <hip/hip_runtime.h>
#include <stdint.h>

// Farthest Point Sampling, B=8, N=131072, npoint=1024.
// 8 batches x 32 WGs x 256 threads. r5 compute structure (LDS coords, 2
// barriers/iter, wave0 orchestrates). The per-iteration sync is XCD-L2-local:
//   r8's FETCH_SIZE fingerprint proved bid&7 does NOT co-locate a batch on
//   one XCD. So roles are now DERIVED FROM HARDWARE: each WG reads XCC_ID,
//   takes an ordinal from a per-XCD counter; a one-time census verifies every
//   XCD got exactly 32 WGs (any balanced permutation works; chunk<->WG is a
//   bijection so output is identical). Then batch = XCD, chunk = ordinal, and
//   slot traffic for batch x stays entirely inside XCD x's coherent L2:
//   publish = asm global_atomic_swap_x2 (no sc1 -> executes at local L2),
//   poll    = asm global_atomic_or_x2 sc0 (RMW: cannot be served stale by L1;
//             intrinsic fetch_or(p,0) risks folding to an L1-cacheable load).
//   Unbalanced dispatch -> r5's proven agent-scope path (correctness never
//   depends on the undefined WG->XCD mapping).
// Winner COORDS travel inside the slot (4 self-tagged words, r7-proven), so
// no serial HBM gather per iteration in either path.

#define NPTS        131072
#define NBATCH      8
#define WGB         32          // chunks (WGs) per batch
#define THREADS     256
#define PPW         4096        // points per chunk
#define SLOT_STRIDE 16          // u64s per slot = 128 B (own cache line)
#define NWG         (NBATCH * WGB)
#define BIGDIST     1e10f

typedef unsigned long long u64;

// Publish at local-L2 point, fire-and-forget (no sc1, no return).
static __device__ __forceinline__ void wg_swap(u64* p, u64 v) {
    asm volatile("global_atomic_swap_x2 %0, %1, off"
                 :: "v"(p), "v"(v) : "memory");
}
// Read two adjacent u64 words at the local-L2 point via idempotent RMW.
static __device__ __forceinline__ void wg_or2(u64* p, u64& a, u64& b) {
    u64 z = 0;
    asm volatile("global_atomic_or_x2 %0, %2, %4, off sc0\n\t"
                 "global_atomic_or_x2 %1, %3, %4, off sc0\n\t"
                 "s_waitcnt vmcnt(0)"
                 : "=&v"(a), "=&v"(b)
                 : "v"(p), "v"(p + 1), "v"(z)
                 : "memory");
}

__global__ __launch_bounds__(THREADS, 1) void fps_kernel(
        const float* __restrict__ xyz,   // [B, N, 3]
        int* __restrict__ out,           // [B, npoint]
        u64* __restrict__ wsbuf,         // slots | census | counters
        int npoint)
{
    const int bid  = blockIdx.x;
    const int tid  = threadIdx.x;
    const int lane = tid & 63;
    const int v    = tid >> 6;            // wave 0..3

    u64* slots  = wsbuf;                                         // [2][NB][WGB][S]
    u64* census = wsbuf + (size_t)2 * NBATCH * WGB * SLOT_STRIDE; // [NWG][S]
    u64* cnt    = census + (size_t)NWG * SLOT_STRIDE;             // [NBATCH][S]

    __shared__ __align__(16) float x_lds[PPW];
    __shared__ __align__(16) float y_lds[PPW];
    __shared__ __align__(16) float z_lds[PPW];
    __shared__ u64   s_w[THREADS / 64];
    __shared__ float s_c[3];
    __shared__ int   s_role;

    // ================= one-time census (wave 0) =================
    if (v == 0) {
        unsigned myxcc = 0, myord = 0;
        if (lane == 0) {
            asm volatile("s_getreg_b32 %0, hwreg(HW_REG_XCC_ID)" : "=s"(myxcc));
            myord = (unsigned)__hip_atomic_fetch_add(
                        cnt + (size_t)(myxcc & 7) * SLOT_STRIDE, 1ull,
                        __ATOMIC_RELAXED, __HIP_MEMORY_SCOPE_AGENT);
            __hip_atomic_store(census + (size_t)bid * SLOT_STRIDE,
                               (0xC0DEC0DEull << 32) |
                                   ((u64)(myxcc & 255u) << 8) | (u64)(myord & 255u),
                               __ATOMIC_RELAXED, __HIP_MEMORY_SCOPE_AGENT);
        }
        // every lane audits 4 of the 256 entries; histogram per-XCD counts
        bool okr = true; u64 acc = 0;
        #pragma unroll
        for (int k = 0; k < 4; ++k) {
            u64* ce = census + (size_t)(lane + 64 * k) * SLOT_STRIDE;
            u64 c;
            do {
                c = __hip_atomic_load(ce, __ATOMIC_RELAXED,
                                      __HIP_MEMORY_SCOPE_AGENT);
            } while ((c >> 32) != 0xC0DEC0DEull);
            unsigned xc = (unsigned)((c >> 8) & 255u);
            okr = okr && (xc < 8u);
            acc += 1ull << (8 * (xc & 7u));
        }
        #pragma unroll
        for (int m = 1; m <= 32; m <<= 1) acc += __shfl_xor(acc, m);
        bool balanced = (acc == 0x2020202020202020ull) &&
                        (__ballot(okr) == ~0ull);
        if (lane == 0)
            s_role = balanced ? ((1 << 16) | (int)((myxcc & 7u) << 8) | (int)myord)
                              : 0;
    }
    __syncthreads();

    const int fast = (s_role >> 16) & 1;
    const int b    = fast ? ((s_role >> 8) & 255) : (bid & 7);
    const int w    = fast ? (s_role & 255)        : (bid >> 3);

    const float* base = xyz + (size_t)b * NPTS * 3;
    const int q0 = w * PPW;               // first batch-point of this chunk

    // ---- one-time fill: thread t loads points t+256j (conflict-free, r5) ----
    #pragma unroll
    for (int j = 0; j < 16; ++j) {
        int q = tid + 256 * j;
        const float* p = base + (size_t)(q0 + q) * 3;
        x_lds[q] = p[0];
        y_lds[q] = p[1];
        z_lds[q] = p[2];
    }

    float dist[16];
    #pragma unroll
    for (int j = 0; j < 16; ++j) dist[j] = BIGDIST;

    float cx = base[0], cy = base[1], cz = base[2];   // centroid 0 = point 0
    if (w == 0 && tid == 0) out[b * npoint + 0] = 0;

    __syncthreads();   // fill visible

    const size_t PAR = (size_t)NBATCH * WGB * SLOT_STRIDE;
    u64* sbase = slots + (size_t)b * WGB * SLOT_STRIDE;

    for (int i = 0; i < npoint - 1; ++i) {
        // ---- distance min-update + per-thread argmax (LDS b128 + VALU, r5) ----
        float bv = -1.0f; int bq = 0;
        {
            #pragma clang fp contract(off)
            #pragma unroll
            for (int g = 0; g < 4; ++g) {
                const int qg = 4 * tid + 1024 * g;
                float4 xv = *reinterpret_cast<const float4*>(&x_lds[qg]);
                float4 yv = *reinterpret_cast<const float4*>(&y_lds[qg]);
                float4 zv = *reinterpret_cast<const float4*>(&z_lds[qg]);
                float xs[4] = { xv.x, xv.y, xv.z, xv.w };
                float ys[4] = { yv.x, yv.y, yv.z, yv.w };
                float zs[4] = { zv.x, zv.y, zv.z, zv.w };
                #pragma unroll
                for (int e = 0; e < 4; ++e) {
                    const int j = 4 * g + e;
                    float dx = xs[e] - cx, dy = ys[e] - cy, dz = zs[e] - cz;
                    float d  = dx*dx + dy*dy + dz*dz;   // mul/add order matches np ref
                    float nd = fminf(dist[j], d);
                    dist[j]  = nd;
                    if (nd > bv) { bv = nd; bq = qg + e; }  // strict >: first max
                }
            }
        }
        u64 pk = ((u64)__float_as_uint(bv) << 32)
               | (u64)(0x1FFFFu - (unsigned)(q0 + bq));

        #pragma unroll
        for (int m = 32; m >= 1; m >>= 1) {
            u64 o = __shfl_xor(pk, m);
            if (o > pk) pk = o;
        }
        if (lane == 0) s_w[v] = pk;
        __syncthreads();

        u64* sb = sbase + ((i & 1) ? PAR : (size_t)0);
        const unsigned tag = (unsigned)(i + 1);   // 1..1023, 10 bits, never 0

        if (v == 0) {
            // ---- combine the 4 wave partials ----
            u64 c = s_w[lane & 3];
            u64 o1 = __shfl_xor(c, 1); if (o1 > c) c = o1;
            u64 o2 = __shfl_xor(c, 2); if (o2 > c) c = o2;

            // ---- lane 0: look up winner coords in own LDS tile, publish 4
            //      self-tagged words: w0=(val,tag,~idx) w1=x w2=y w3=z ----
            if (lane == 0) {
                int idx_wg = (int)(0x1FFFFu - (unsigned)(c & 0x1FFFFu));
                int qw = idx_wg - q0;                      // 0..4095, ours
                u64 tw = ((u64)tag << 32);
                u64 w1 = tw | (u64)__float_as_uint(x_lds[qw]);
                u64 w2 = tw | (u64)__float_as_uint(y_lds[qw]);
                u64 w3 = tw | (u64)__float_as_uint(z_lds[qw]);
                u64 w0 = c | ((u64)tag << 22);
                u64* my = sb + (size_t)w * SLOT_STRIDE;
                if (fast) {
                    wg_swap(my + 1, w1); wg_swap(my + 2, w2);
                    wg_swap(my + 3, w3); wg_swap(my + 0, w0);
                } else {
                    __hip_atomic_store(my + 1, w1, __ATOMIC_RELAXED, __HIP_MEMORY_SCOPE_AGENT);
                    __hip_atomic_store(my + 2, w2, __ATOMIC_RELAXED, __HIP_MEMORY_SCOPE_AGENT);
                    __hip_atomic_store(my + 3, w3, __ATOMIC_RELAXED, __HIP_MEMORY_SCOPE_AGENT);
                    __hip_atomic_store(my + 0, w0, __ATOMIC_RELAXED, __HIP_MEMORY_SCOPE_AGENT);
                }
            }

            // ---- poll: lane pair (2s,2s+1) covers slot s; even lane words
            //      0,1 ; odd lane words 2,3. Every word self-tagged. ----
            const int  s    = lane >> 1;
            const bool even = (lane & 1) == 0;
            u64* sp = sb + (size_t)s * SLOT_STRIDE + (even ? 0 : 2);
            u64 wa = 0, wb = 0;
            bool oka = false, okb = false;
            if (fast) {
                do {
                    wg_or2(sp, wa, wb);
                    oka = (even ? (unsigned)((wa >> 22) & 1023u)
                                : (unsigned)((wa >> 32) & 1023u)) == tag;
                    okb = ((unsigned)((wb >> 32) & 1023u) == tag);
                } while (__ballot(oka && okb) != ~0ull);
            } else {
                do {
                    if (!oka) {
                        wa = __hip_atomic_load(sp + 0, __ATOMIC_RELAXED,
                                               __HIP_MEMORY_SCOPE_AGENT);
                        oka = (even ? (unsigned)((wa >> 22) & 1023u)
                                    : (unsigned)((wa >> 32) & 1023u)) == tag;
                    }
                    if (!okb) {
                        wb = __hip_atomic_load(sp + 1, __ATOMIC_RELAXED,
                                               __HIP_MEMORY_SCOPE_AGENT);
                        okb = ((unsigned)((wb >> 32) & 1023u) == tag);
                    }
                } while (__ballot(oka && okb) != ~0ull);
            }

            // ---- butterfly max over w0 (even lanes carry candidates) ----
            u64 mx = even ? wa : 0;     // w0 >= tag<<22 > 0, so 0 never wins
            #pragma unroll
            for (int m = 32; m >= 1; m >>= 1) {
                u64 o = __shfl_xor(mx, m);
                if (o > mx) mx = o;
            }
            int idx_win = (int)(0x1FFFFu - (unsigned)(mx & 0x1FFFFu));
            int sw = idx_win >> 12;                  // winner chunk = idx / 4096

            // coords from slot words: even lane 2sw holds x(wb); odd 2sw+1 y(wa),z(wb)
            float fxx = even ? __uint_as_float((unsigned)wb) : 0.f;
            float fyy = even ? 0.f : __uint_as_float((unsigned)wa);
            float fzz = even ? 0.f : __uint_as_float((unsigned)wb);
            float nx = __shfl(fxx, 2 * sw);
            float ny = __shfl(fyy, 2 * sw + 1);
            float nz = __shfl(fzz, 2 * sw + 1);
            if (lane == 0) {
                s_c[0] = nx; s_c[1] = ny; s_c[2] = nz;
                if (w == 0) out[b * npoint + (i + 1)] = idx_win;
            }
        }
        __syncthreads();

        cx = s_c[0]; cy = s_c[1]; cz = s_c[2];
    }
}

extern "C" void kernel_launch(void* const* d_in, const int* in_sizes, int n_in,
                              void* d_out, int out_size, void* d_ws, size_t ws_size,
                              hipStream_t stream) {
    const float* xyz = (const float*)d_in[0];
    int* out = (int*)d_out;
    u64* wsbuf = (u64*)d_ws;
    const int npoint = out_size / NBATCH;   // 1024

    // Clear slots + census + counters (~97 KB): stale tags can never match.
    hipMemsetAsync(d_ws, 0,
                   (size_t)(2 * NBATCH * WGB + NWG + NBATCH) * SLOT_STRIDE * sizeof(u64),
                   stream);

    dim3 grid(NWG);   // 256 WGs <= 256 CUs -> all co-resident, spin-sync safe
    dim3 block(THREADS);
    fps_kernel<<<grid, block, 0, stream>>>(xyz, out, wsbuf, npoint);
}

// Round 10
// 3122.310 us; speedup vs baseline: 1.0306x; 1.0306x over previous
//
#include <hip/hip_runtime.h>
#include <stdint.h>

// Farthest Point Sampling, B=8, N=131072, npoint=1024.
// 8 batches x 32 WGs x 256 threads. r5's proven compute structure (LDS SoA
// coords, conflict-free 4*tid ds_read_b128 update, 2 barriers/iter) +
// r7's proven sync protocol (winner coords ride inside the slot as 4
// self-tagged u64 words), with r7's failed register-pin experiment removed
// (it caused scratch spills + LDS bank conflicts that masked the gain).
//
// Hardware facts driving this design (measured r5/r8/r9):
//  - slot atomics are serviced at the memory-side coherence point: polls are
//    ~fabric-latency regardless of scope bits; RMW polling writes 1.26 GB
//    (r9) -> plain relaxed agent-scope load/store only.
//  - the serial per-iteration winner-coord gather base[idx*3] is one extra
//    fabric RT on the critical path -> coords travel inside the slot.
//  - hipcc rematerializes/spills any attempt at VGPR-resident coords
//    (r2-r4, r6, r7) -> coords live in LDS, dist[] in VGPRs.

#define NPTS        131072
#define NBATCH      8
#define WGB         32          // workgroups per batch
#define THREADS     256
#define PPW         4096        // points per WG
#define SLOT_STRIDE 16          // u64s per slot = 128 B (own cache line)
#define BIGDIST     1e10f

typedef unsigned long long u64;

__global__ __launch_bounds__(THREADS, 1) void fps_kernel(
        const float* __restrict__ xyz,   // [B, N, 3]
        int* __restrict__ out,           // [B, npoint]
        u64* __restrict__ slots,         // [2][NBATCH][WGB][SLOT_STRIDE]
        int npoint)
{
    const int bid  = blockIdx.x;
    const int b    = bid & (NBATCH - 1);
    const int w    = bid >> 3;            // 0..31 WG-within-batch
    const int tid  = threadIdx.x;
    const int lane = tid & 63;
    const int v    = tid >> 6;            // wave 0..3

    const float* base = xyz + (size_t)b * NPTS * 3;
    const int q0 = w * PPW;               // first batch-point of this WG

    __shared__ __align__(16) float x_lds[PPW];
    __shared__ __align__(16) float y_lds[PPW];
    __shared__ __align__(16) float z_lds[PPW];
    __shared__ u64   s_w[THREADS / 64];
    __shared__ float s_c[3];

    // ---- one-time fill: thread t loads points t+256j (conflict-free) ----
    #pragma unroll
    for (int j = 0; j < 16; ++j) {
        int q = tid + 256 * j;                      // 0..4095 within WG
        const float* p = base + (size_t)(q0 + q) * 3;
        x_lds[q] = p[0];
        y_lds[q] = p[1];
        z_lds[q] = p[2];
    }

    float dist[16];
    #pragma unroll
    for (int j = 0; j < 16; ++j) dist[j] = BIGDIST;

    float cx = base[0], cy = base[1], cz = base[2];   // centroid 0 = point 0
    if (w == 0 && tid == 0) out[b * npoint + 0] = 0;

    __syncthreads();   // fill visible to all waves

    const size_t PAR = (size_t)NBATCH * WGB * SLOT_STRIDE;   // parity block (u64s)
    u64* sbase = slots + (size_t)b * WGB * SLOT_STRIDE;

    for (int i = 0; i < npoint - 1; ++i) {
        // ---- distance min-update + per-thread argmax (LDS b128 + VALU) ----
        float bv = -1.0f; int bq = 0;   // bq: point index within WG (0..4095)
        {
            #pragma clang fp contract(off)
            #pragma unroll
            for (int g = 0; g < 4; ++g) {
                const int qg = 4 * tid + 1024 * g;
                float4 xv = *reinterpret_cast<const float4*>(&x_lds[qg]);
                float4 yv = *reinterpret_cast<const float4*>(&y_lds[qg]);
                float4 zv = *reinterpret_cast<const float4*>(&z_lds[qg]);
                float xs[4] = { xv.x, xv.y, xv.z, xv.w };
                float ys[4] = { yv.x, yv.y, yv.z, yv.w };
                float zs[4] = { zv.x, zv.y, zv.z, zv.w };
                #pragma unroll
                for (int e = 0; e < 4; ++e) {
                    const int j = 4 * g + e;
                    float dx = xs[e] - cx, dy = ys[e] - cy, dz = zs[e] - cz;
                    float d  = dx*dx + dy*dy + dz*dz;   // mul/add order matches np ref
                    float nd = fminf(dist[j], d);
                    dist[j]  = nd;
                    if (nd > bv) { bv = nd; bq = qg + e; }  // strict >: first max
                }
            }
        }
        // pack: [63:32] val bits (non-neg -> order-preserving)
        //       [16:0]  131071 - idx (bigger packed == smaller idx on tie)
        //       [31:22] tag added at publish
        u64 pk = ((u64)__float_as_uint(bv) << 32)
               | (u64)(0x1FFFFu - (unsigned)(q0 + bq));

        #pragma unroll
        for (int m = 32; m >= 1; m >>= 1) {
            u64 o = __shfl_xor(pk, m);
            if (o > pk) pk = o;
        }
        if (lane == 0) s_w[v] = pk;
        __syncthreads();

        u64* sb = sbase + ((i & 1) ? PAR : (size_t)0);
        const unsigned tag = (unsigned)(i + 1);   // 1..1023, 10 bits, never 0

        if (v == 0) {
            // ---- combine the 4 wave partials (all lanes end with WG best) ----
            u64 c = s_w[lane & 3];
            u64 o1 = __shfl_xor(c, 1); if (o1 > c) c = o1;
            u64 o2 = __shfl_xor(c, 2); if (o2 > c) c = o2;

            // ---- lane 0: look up candidate coords in OWN LDS tile, publish
            //      4 self-tagged words: w0=(val,tag,~idx) w1=x w2=y w3=z ----
            if (lane == 0) {
                int idx_wg = (int)(0x1FFFFu - (unsigned)(c & 0x1FFFFu));
                int qw = idx_wg - q0;                      // 0..4095, ours
                u64 tw = ((u64)tag << 32);
                u64* my = sb + (size_t)w * SLOT_STRIDE;
                __hip_atomic_store(my + 1, tw | (u64)__float_as_uint(x_lds[qw]),
                                   __ATOMIC_RELAXED, __HIP_MEMORY_SCOPE_AGENT);
                __hip_atomic_store(my + 2, tw | (u64)__float_as_uint(y_lds[qw]),
                                   __ATOMIC_RELAXED, __HIP_MEMORY_SCOPE_AGENT);
                __hip_atomic_store(my + 3, tw | (u64)__float_as_uint(z_lds[qw]),
                                   __ATOMIC_RELAXED, __HIP_MEMORY_SCOPE_AGENT);
                __hip_atomic_store(my + 0, c | ((u64)tag << 22),
                                   __ATOMIC_RELAXED, __HIP_MEMORY_SCOPE_AGENT);
            }

            // ---- poll: lane pair (2s,2s+1) covers slot s; even lane reads
            //      words 0,1 ; odd lane reads words 2,3. All self-tagged. ----
            const int  s    = lane >> 1;
            const bool even = (lane & 1) == 0;
            u64* sp = sb + (size_t)s * SLOT_STRIDE + (even ? 0 : 2);
            u64 wa = 0, wb = 0;
            bool oka = false, okb = false;
            do {
                if (!oka) {
                    wa = __hip_atomic_load(sp + 0, __ATOMIC_RELAXED,
                                           __HIP_MEMORY_SCOPE_AGENT);
                    oka = (even ? (unsigned)((wa >> 22) & 1023u)
                                : (unsigned)((wa >> 32) & 1023u)) == tag;
                }
                if (!okb) {
                    wb = __hip_atomic_load(sp + 1, __ATOMIC_RELAXED,
                                           __HIP_MEMORY_SCOPE_AGENT);
                    okb = ((unsigned)((wb >> 32) & 1023u) == tag);
                }
            } while (__ballot(oka && okb) != ~0ull);

            // ---- butterfly max over w0 (even lanes carry candidates) ----
            u64 mx = even ? wa : 0;     // w0 >= tag<<22 > 0, so 0 never wins
            #pragma unroll
            for (int m = 32; m >= 1; m >>= 1) {
                u64 o = __shfl_xor(mx, m);
                if (o > mx) mx = o;
            }
            int idx_win = (int)(0x1FFFFu - (unsigned)(mx & 0x1FFFFu));
            int sw = idx_win >> 12;                  // winner slot = idx / 4096

            // coords: even lane 2sw holds x (wb=word1); odd 2sw+1 holds y(wa),z(wb)
            float fxx = even ? __uint_as_float((unsigned)wb) : 0.f;
            float fyy = even ? 0.f : __uint_as_float((unsigned)wa);
            float fzz = even ? 0.f : __uint_as_float((unsigned)wb);
            float nx = __shfl(fxx, 2 * sw);
            float ny = __shfl(fyy, 2 * sw + 1);
            float nz = __shfl(fzz, 2 * sw + 1);
            if (lane == 0) {
                s_c[0] = nx; s_c[1] = ny; s_c[2] = nz;
                if (w == 0) out[b * npoint + (i + 1)] = idx_win;
            }
        }
        __syncthreads();

        cx = s_c[0]; cy = s_c[1]; cz = s_c[2];
    }
}

extern "C" void kernel_launch(void* const* d_in, const int* in_sizes, int n_in,
                              void* d_out, int out_size, void* d_ws, size_t ws_size,
                              hipStream_t stream) {
    const float* xyz = (const float*)d_in[0];
    int* out = (int*)d_out;
    u64* slots = (u64*)d_ws;
    const int npoint = out_size / NBATCH;   // 1024

    // Clear slot region (64 KB) so stale/poisoned tags can never match tag>=1.
    hipMemsetAsync(d_ws, 0,
                   (size_t)2 * NBATCH * WGB * SLOT_STRIDE * sizeof(u64),
                   stream);

    dim3 grid(NBATCH * WGB);   // 256 WGs <= 256 CUs -> all co-resident, spin-sync safe
    dim3 block(THREADS);
    fps_kernel<<<grid, block, 0, stream>>>(xyz, out, slots, npoint);
}

// Round 11
// 2553.374 us; speedup vs baseline: 1.2602x; 1.2228x over previous
//
#include <hip/hip_runtime.h>
#include <stdint.h>

// Farthest Point Sampling, B=8, N=131072, npoint=1024.
// 8 batches x 32 WGs x 256 threads. r5's proven compute structure (LDS SoA
// coords, conflict-free 4*tid ds_read_b128 update, 2 barriers/iter).
// Sync: winner coords ride inside the slot (4 self-tagged u64 words), but
// polled as TWO 16-byte global_load_dwordx4 transactions (even lane: w0,w1;
// odd lane: w2,w3) -- r10 proved per-u64 atomic polling (128 transactions/
// round) regresses vs r5's 32; dwordx4 keeps transaction count ~= r5 while
// removing the serial winner-coord HBM gather from the critical path.
// Loads/stores use asm 'sc0 sc1' (system-scope cache bypass on gfx950):
// polls can never be served by a stale private cache, and per-word self-tags
// make transiently-stale data safe (re-poll).
// Measured facts driving this: slot atomics are memory-side serviced (r5/r8);
// RMW polling writes GBs (r9); hipcc won't keep coords in VGPRs (r2-r7).

#define NPTS        131072
#define NBATCH      8
#define WGB         32          // workgroups per batch
#define THREADS     256
#define PPW         4096        // points per WG
#define SLOT_STRIDE 16          // u64s per slot = 128 B (own cache line)
#define BIGDIST     1e10f

typedef unsigned long long u64;
typedef unsigned int u32x4 __attribute__((ext_vector_type(4)));

// 16B system-scope load: one transaction, bypasses L1/L2 (sc0 sc1).
static __device__ __forceinline__ u32x4 load16_sys(const u64* p) {
    u32x4 r;
    asm volatile("global_load_dwordx4 %0, %1, off sc0 sc1\n\t"
                 "s_waitcnt vmcnt(0)"
                 : "=v"(r) : "v"(p) : "memory");
    return r;
}
// 16B system-scope store: one transaction, write-through past private caches.
static __device__ __forceinline__ void store16_sys(u64* p, u64 a, u64 b) {
    u32x4 q;
    q.x = (unsigned)a; q.y = (unsigned)(a >> 32);
    q.z = (unsigned)b; q.w = (unsigned)(b >> 32);
    asm volatile("global_store_dwordx4 %0, %1, off sc0 sc1"
                 :: "v"(p), "v"(q) : "memory");
}

__global__ __launch_bounds__(THREADS, 1) void fps_kernel(
        const float* __restrict__ xyz,   // [B, N, 3]
        int* __restrict__ out,           // [B, npoint]
        u64* __restrict__ slots,         // [2][NBATCH][WGB][SLOT_STRIDE]
        int npoint)
{
    const int bid  = blockIdx.x;
    const int b    = bid & (NBATCH - 1);
    const int w    = bid >> 3;            // 0..31 WG-within-batch
    const int tid  = threadIdx.x;
    const int lane = tid & 63;
    const int v    = tid >> 6;            // wave 0..3

    const float* base = xyz + (size_t)b * NPTS * 3;
    const int q0 = w * PPW;               // first batch-point of this WG

    __shared__ __align__(16) float x_lds[PPW];
    __shared__ __align__(16) float y_lds[PPW];
    __shared__ __align__(16) float z_lds[PPW];
    __shared__ u64   s_w[THREADS / 64];
    __shared__ float s_c[3];

    // ---- one-time fill: thread t loads points t+256j (conflict-free) ----
    #pragma unroll
    for (int j = 0; j < 16; ++j) {
        int q = tid + 256 * j;                      // 0..4095 within WG
        const float* p = base + (size_t)(q0 + q) * 3;
        x_lds[q] = p[0];
        y_lds[q] = p[1];
        z_lds[q] = p[2];
    }

    float dist[16];
    #pragma unroll
    for (int j = 0; j < 16; ++j) dist[j] = BIGDIST;

    float cx = base[0], cy = base[1], cz = base[2];   // centroid 0 = point 0
    if (w == 0 && tid == 0) out[b * npoint + 0] = 0;

    __syncthreads();   // fill visible to all waves

    const size_t PAR = (size_t)NBATCH * WGB * SLOT_STRIDE;   // parity block (u64s)
    u64* sbase = slots + (size_t)b * WGB * SLOT_STRIDE;

    for (int i = 0; i < npoint - 1; ++i) {
        // ---- distance min-update + per-thread argmax (LDS b128 + VALU) ----
        float bv = -1.0f; int bq = 0;   // bq: point index within WG (0..4095)
        {
            #pragma clang fp contract(off)
            #pragma unroll
            for (int g = 0; g < 4; ++g) {
                const int qg = 4 * tid + 1024 * g;
                float4 xv = *reinterpret_cast<const float4*>(&x_lds[qg]);
                float4 yv = *reinterpret_cast<const float4*>(&y_lds[qg]);
                float4 zv = *reinterpret_cast<const float4*>(&z_lds[qg]);
                float xs[4] = { xv.x, xv.y, xv.z, xv.w };
                float ys[4] = { yv.x, yv.y, yv.z, yv.w };
                float zs[4] = { zv.x, zv.y, zv.z, zv.w };
                #pragma unroll
                for (int e = 0; e < 4; ++e) {
                    const int j = 4 * g + e;
                    float dx = xs[e] - cx, dy = ys[e] - cy, dz = zs[e] - cz;
                    float d  = dx*dx + dy*dy + dz*dz;   // mul/add order matches np ref
                    float nd = fminf(dist[j], d);
                    dist[j]  = nd;
                    if (nd > bv) { bv = nd; bq = qg + e; }  // strict >: first max
                }
            }
        }
        // pack: [63:32] val bits (non-neg -> order-preserving)
        //       [16:0]  131071 - idx (bigger packed == smaller idx on tie)
        //       [31:22] tag added at publish
        u64 pk = ((u64)__float_as_uint(bv) << 32)
               | (u64)(0x1FFFFu - (unsigned)(q0 + bq));

        #pragma unroll
        for (int m = 32; m >= 1; m >>= 1) {
            u64 o = __shfl_xor(pk, m);
            if (o > pk) pk = o;
        }
        if (lane == 0) s_w[v] = pk;
        __syncthreads();

        u64* sb = sbase + ((i & 1) ? PAR : (size_t)0);
        const unsigned tag = (unsigned)(i + 1);   // 1..1023, 10 bits, never 0

        if (v == 0) {
            // ---- combine the 4 wave partials (all lanes end with WG best) ----
            u64 c = s_w[lane & 3];
            u64 o1 = __shfl_xor(c, 1); if (o1 > c) c = o1;
            u64 o2 = __shfl_xor(c, 2); if (o2 > c) c = o2;

            // ---- lane 0: look up candidate coords in OWN LDS tile, publish
            //      4 self-tagged words as two 16B stores:
            //      w0=(val,tag@22,~idx)  w1=tag@32|x  w2=tag@32|y  w3=tag@32|z
            if (lane == 0) {
                int idx_wg = (int)(0x1FFFFu - (unsigned)(c & 0x1FFFFu));
                int qw = idx_wg - q0;                      // 0..4095, ours
                u64 tw = ((u64)tag << 32);
                u64* my = sb + (size_t)w * SLOT_STRIDE;
                u64 w0 = c | ((u64)tag << 22);
                u64 w1 = tw | (u64)__float_as_uint(x_lds[qw]);
                u64 w2 = tw | (u64)__float_as_uint(y_lds[qw]);
                u64 w3 = tw | (u64)__float_as_uint(z_lds[qw]);
                store16_sys(my + 0, w0, w1);
                store16_sys(my + 2, w2, w3);
            }

            // ---- poll: lane pair (2s,2s+1) covers slot s with ONE dwordx4
            //      each: even lane words 0,1 ; odd lane words 2,3 ----
            const int  s    = lane >> 1;
            const bool even = (lane & 1) == 0;
            u64* sp = sb + (size_t)s * SLOT_STRIDE + (even ? 0 : 2);
            u64 wa = 0, wb = 0;
            bool ok = false;
            do {
                u32x4 r = load16_sys(sp);
                wa = ((u64)r.y << 32) | r.x;
                wb = ((u64)r.w << 32) | r.z;
                unsigned ta = even ? (unsigned)((wa >> 22) & 1023u)
                                   : (unsigned)((wa >> 32) & 1023u);
                unsigned tb = (unsigned)((wb >> 32) & 1023u);
                ok = (ta == tag) && (tb == tag);
            } while (__ballot(ok) != ~0ull);

            // ---- butterfly max over w0 (even lanes carry candidates) ----
            u64 mx = even ? wa : 0;     // w0 >= tag<<22 > 0, so 0 never wins
            #pragma unroll
            for (int m = 32; m >= 1; m >>= 1) {
                u64 o = __shfl_xor(mx, m);
                if (o > mx) mx = o;
            }
            int idx_win = (int)(0x1FFFFu - (unsigned)(mx & 0x1FFFFu));
            int sw = idx_win >> 12;                  // winner slot = idx / 4096

            // coords: even lane 2sw holds x (wb=w1); odd 2sw+1 holds y(wa),z(wb)
            float fxx = even ? __uint_as_float((unsigned)wb) : 0.f;
            float fyy = even ? 0.f : __uint_as_float((unsigned)wa);
            float fzz = even ? 0.f : __uint_as_float((unsigned)wb);
            float nx = __shfl(fxx, 2 * sw);
            float ny = __shfl(fyy, 2 * sw + 1);
            float nz = __shfl(fzz, 2 * sw + 1);
            if (lane == 0) {
                s_c[0] = nx; s_c[1] = ny; s_c[2] = nz;
                if (w == 0) out[b * npoint + (i + 1)] = idx_win;
            }
        }
        __syncthreads();

        cx = s_c[0]; cy = s_c[1]; cz = s_c[2];
    }
}

extern "C" void kernel_launch(void* const* d_in, const int* in_sizes, int n_in,
                              void* d_out, int out_size, void* d_ws, size_t ws_size,
                              hipStream_t stream) {
    const float* xyz = (const float*)d_in[0];
    int* out = (int*)d_out;
    u64* slots = (u64*)d_ws;
    const int npoint = out_size / NBATCH;   // 1024

    // Clear slot region (64 KB) so stale/poisoned tags can never match tag>=1.
    hipMemsetAsync(d_ws, 0,
                   (size_t)2 * NBATCH * WGB * SLOT_STRIDE * sizeof(u64),
                   stream);

    dim3 grid(NBATCH * WGB);   // 256 WGs <= 256 CUs -> all co-resident, spin-sync safe
    dim3 block(THREADS);
    fps_kernel<<<grid, block, 0, stream>>>(xyz, out, slots, npoint);
}

// Round 12
// 2501.678 us; speedup vs baseline: 1.2862x; 1.0207x over previous
//
#include <hip/hip_runtime.h>
#include <stdint.h>

// Farthest Point Sampling, B=8, N=131072, npoint=1024.
// 8 batches x 32 WGs x 256 threads. r5's compute + r5's EXACT fabric sync
// (32 padded WG-slots, relaxed agent-scope 8B atomics, wave0 polls with
// speculative winner gather -- r10/r11 proved the gather is already
// overlapped and every "improvement" on the fabric pattern regresses).
// NEW: zero __syncthreads in the main loop. Intra-WG coordination is done
// with self-tagged LDS words (ds atomics are CU-coherent; tag+zero-init
// makes them order-free):
//   partials:  wave v lane0 ds_writes s_w[v]=(val|tag@22|~idx);
//              wave0 lanes0-3 spin-read, combine, publish to fabric.
//   winner:    wave0 lanes0-2 ds_write s_cw[]=(tag@32|coord);
//              waves1-3 spin-read (s_sleep backoff to spare the LDS pipe,
//              which wave0's ds_bpermute butterflies need).
// Chain dependency (wave v can't produce iter i+1 before consuming iter i's
// winner, which wave0 can't produce before consuming iter i's partials)
// guarantees no handshake word is overwritten before it is consumed.

#define NPTS        131072
#define NBATCH      8
#define WGB         32          // workgroups per batch
#define THREADS     256
#define PPW         4096        // points per WG
#define SLOT_STRIDE 16          // u64s per slot = 128 B (own cache line)
#define BIGDIST     1e10f

typedef unsigned long long u64;

__global__ __launch_bounds__(THREADS, 1) void fps_kernel(
        const float* __restrict__ xyz,   // [B, N, 3]
        int* __restrict__ out,           // [B, npoint]
        u64* __restrict__ slots,         // [2][NBATCH][WGB][SLOT_STRIDE]
        int npoint)
{
    const int bid  = blockIdx.x;
    const int b    = bid & (NBATCH - 1);
    const int w    = bid >> 3;            // 0..31 WG-within-batch
    const int tid  = threadIdx.x;
    const int lane = tid & 63;
    const int v    = tid >> 6;            // wave 0..3

    const float* base = xyz + (size_t)b * NPTS * 3;
    const int q0 = w * PPW;               // first batch-point of this WG

    __shared__ __align__(16) float x_lds[PPW];
    __shared__ __align__(16) float y_lds[PPW];
    __shared__ __align__(16) float z_lds[PPW];
    __shared__ u64 s_w[4];                // per-wave tagged partials
    __shared__ u64 s_cw[3];               // tagged winner coords x,y,z

    // ---- one-time fill: thread t loads points t+256j (conflict-free) ----
    #pragma unroll
    for (int j = 0; j < 16; ++j) {
        int q = tid + 256 * j;                      // 0..4095 within WG
        const float* p = base + (size_t)(q0 + q) * 3;
        x_lds[q] = p[0];
        y_lds[q] = p[1];
        z_lds[q] = p[2];
    }
    if (tid < 4) s_w[tid] = 0;            // stale-tag proofing
    if (tid < 3) s_cw[tid] = 0;

    float dist[16];
    #pragma unroll
    for (int j = 0; j < 16; ++j) dist[j] = BIGDIST;

    float cx = base[0], cy = base[1], cz = base[2];   // centroid 0 = point 0
    if (w == 0 && tid == 0) out[b * npoint + 0] = 0;

    __syncthreads();   // the ONLY barrier: fill + handshake-init visible

    const size_t PAR = (size_t)NBATCH * WGB * SLOT_STRIDE;   // parity block
    u64* sbase = slots + (size_t)b * WGB * SLOT_STRIDE;

    for (int i = 0; i < npoint - 1; ++i) {
        // ---- distance min-update + per-thread argmax (LDS b128 + VALU) ----
        float bv = -1.0f; int bq = 0;   // bq: point index within WG (0..4095)
        {
            #pragma clang fp contract(off)
            #pragma unroll
            for (int g = 0; g < 4; ++g) {
                const int qg = 4 * tid + 1024 * g;
                float4 xv = *reinterpret_cast<const float4*>(&x_lds[qg]);
                float4 yv = *reinterpret_cast<const float4*>(&y_lds[qg]);
                float4 zv = *reinterpret_cast<const float4*>(&z_lds[qg]);
                float xs[4] = { xv.x, xv.y, xv.z, xv.w };
                float ys[4] = { yv.x, yv.y, yv.z, yv.w };
                float zs[4] = { zv.x, zv.y, zv.z, zv.w };
                #pragma unroll
                for (int e = 0; e < 4; ++e) {
                    const int j = 4 * g + e;
                    float dx = xs[e] - cx, dy = ys[e] - cy, dz = zs[e] - cz;
                    float d  = dx*dx + dy*dy + dz*dz;   // mul/add order matches np ref
                    float nd = fminf(dist[j], d);
                    dist[j]  = nd;
                    if (nd > bv) { bv = nd; bq = qg + e; }  // strict >: first max
                }
            }
        }
        const unsigned tag = (unsigned)(i + 1);   // 1..1023, 10 bits, never 0
        // pack: [63:32] val bits | [31:22] tag | [16:0] 131071-idx
        u64 pk = ((u64)__float_as_uint(bv) << 32)
               | ((u64)tag << 22)
               | (u64)(0x1FFFFu - (unsigned)(q0 + bq));

        #pragma unroll
        for (int m = 32; m >= 1; m >>= 1) {
            u64 o = __shfl_xor(pk, m);
            if (o > pk) pk = o;
        }
        // ---- wave v lane0: hand partial to wave0 via tagged LDS word ----
        if (lane == 0)
            __hip_atomic_store(&s_w[v], pk, __ATOMIC_RELAXED,
                               __HIP_MEMORY_SCOPE_WORKGROUP);

        u64* sb = sbase + ((i & 1) ? PAR : (size_t)0);

        if (v == 0) {
            // ---- lanes 0-3: spin on the 4 tagged partials ----
            u64 c = 0;
            if (lane < 4) {
                do {
                    c = __hip_atomic_load(&s_w[lane], __ATOMIC_RELAXED,
                                          __HIP_MEMORY_SCOPE_WORKGROUP);
                } while (((unsigned)(c >> 22) & 1023u) != tag);
            }
            u64 o1 = __shfl_xor(c, 1); if (o1 > c) c = o1;
            u64 o2 = __shfl_xor(c, 2); if (o2 > c) c = o2;

            // ---- lane 0 publishes WG winner to fabric (r5 exact) ----
            if (lane == 0)
                __hip_atomic_store(sb + (size_t)w * SLOT_STRIDE, c,
                                   __ATOMIC_RELAXED, __HIP_MEMORY_SCOPE_AGENT);

            // ---- poll all 32 slots; speculative gather overlaps (r5 exact) ----
            u64 s = 0;
            if (lane < WGB) {
                u64* sl = sb + (size_t)lane * SLOT_STRIDE;
                do {
                    s = __hip_atomic_load(sl, __ATOMIC_RELAXED,
                                          __HIP_MEMORY_SCOPE_AGENT);
                } while (((unsigned)(s >> 22) & 1023u) != tag);
            }
            int idx_l = (int)(0x1FFFFu - (unsigned)(s & 0x1FFFFu));
            float ccx = 0.f, ccy = 0.f, ccz = 0.f;
            if (lane < WGB) {
                const float* cp = base + (size_t)idx_l * 3;
                ccx = cp[0]; ccy = cp[1]; ccz = cp[2];
            }
            u64 mx = s;
            #pragma unroll
            for (int m = 32; m >= 1; m >>= 1) {
                u64 o = __shfl_xor(mx, m);
                if (o > mx) mx = o;
            }
            u64 ball = __ballot(lane < WGB && s == mx);
            int winlane = __ffsll(ball) - 1;
            cx = __shfl(ccx, winlane);
            cy = __shfl(ccy, winlane);
            cz = __shfl(ccz, winlane);
            int wix = __shfl(idx_l, winlane);

            // ---- lanes 0-2: broadcast winner coords via tagged LDS ----
            float my3[3] = { cx, cy, cz };
            if (lane < 3)
                __hip_atomic_store(&s_cw[lane],
                                   ((u64)tag << 32) |
                                       (u64)__float_as_uint(my3[lane]),
                                   __ATOMIC_RELAXED, __HIP_MEMORY_SCOPE_WORKGROUP);
            if (w == 0 && lane == 0) out[b * npoint + (i + 1)] = wix;
        } else {
            // ---- waves 1-3: spin on the 3 tagged coord words ----
            u64 c0, c1, c2;
            bool k0 = false, k1 = false, k2 = false;
            do {
                __builtin_amdgcn_s_sleep(1);   // spare the LDS pipe for wave0
                if (!k0) { c0 = __hip_atomic_load(&s_cw[0], __ATOMIC_RELAXED,
                                   __HIP_MEMORY_SCOPE_WORKGROUP);
                           k0 = ((unsigned)(c0 >> 32) == tag); }
                if (!k1) { c1 = __hip_atomic_load(&s_cw[1], __ATOMIC_RELAXED,
                                   __HIP_MEMORY_SCOPE_WORKGROUP);
                           k1 = ((unsigned)(c1 >> 32) == tag); }
                if (!k2) { c2 = __hip_atomic_load(&s_cw[2], __ATOMIC_RELAXED,
                                   __HIP_MEMORY_SCOPE_WORKGROUP);
                           k2 = ((unsigned)(c2 >> 32) == tag); }
            } while (!(k0 && k1 && k2));
            cx = __uint_as_float((unsigned)c0);
            cy = __uint_as_float((unsigned)c1);
            cz = __uint_as_float((unsigned)c2);
        }
    }
}

extern "C" void kernel_launch(void* const* d_in, const int* in_sizes, int n_in,
                              void* d_out, int out_size, void* d_ws, size_t ws_size,
                              hipStream_t stream) {
    const float* xyz = (const float*)d_in[0];
    int* out = (int*)d_out;
    u64* slots = (u64*)d_ws;
    const int npoint = out_size / NBATCH;   // 1024

    // Clear slot region (64 KB) so stale/poisoned tags can never match tag>=1.
    hipMemsetAsync(d_ws, 0,
                   (size_t)2 * NBATCH * WGB * SLOT_STRIDE * sizeof(u64),
                   stream);

    dim3 grid(NBATCH * WGB);   // 256 WGs <= 256 CUs -> all co-resident, spin-sync safe
    dim3 block(THREADS);
    fps_kernel<<<grid, block, 0, stream>>>(xyz, out, slots, npoint);
}